// Round 2
// baseline (36631.482 us; speedup 1.0000x reference)
//
#include <hip/hip_runtime.h>
#include <cmath>

#define Bsz 64
#define Tsz 256
#define Hsz 1024
#define NWG 256
#define NTHR 256
#define GRPWG 64   // workgroups per b-group (4 groups of 64)

// ---------------- device-global scratch (avoids ws_size uncertainty) --------
__device__ float g_h[2][2][Bsz * Hsz];      // [layer][parity][b*H+k]
__device__ float g_preW[2][64][64];         // [parity][jg][b] gate partials
__device__ float g_an[Bsz * Tsz];           // xnext . v1 per (b,t)
__device__ float g_v1[Hsz];
__device__ float g_v2[Hsz];
__device__ float g_c;
__device__ unsigned g_bar_cnt[4 * 32];      // padded per-group barrier state
__device__ unsigned g_bar_gen[4 * 32];

// ---------------- group barrier (64 WGs, device-scope) ----------------------
__device__ __forceinline__ void groupbar(int bg, unsigned lgen) {
    __syncthreads();
    if (threadIdx.x == 0) {
        __threadfence();  // publish our writes device-wide (L2 WB)
        unsigned* cnt = &g_bar_cnt[bg * 32];
        unsigned* gen = &g_bar_gen[bg * 32];
        unsigned prev = atomicAdd(cnt, 1u);
        if (prev == GRPWG - 1) {
            __hip_atomic_store(cnt, 0u, __ATOMIC_RELAXED, __HIP_MEMORY_SCOPE_AGENT);
            __hip_atomic_store(gen, lgen, __ATOMIC_RELEASE, __HIP_MEMORY_SCOPE_AGENT);
        } else {
            while (__hip_atomic_load(gen, __ATOMIC_ACQUIRE, __HIP_MEMORY_SCOPE_AGENT) < lgen) {
                __builtin_amdgcn_s_sleep(1);
            }
        }
        __threadfence();  // acquire: invalidate stale cache lines
    }
    __syncthreads();
}

// ---------------- init: h buffers, v1/v2/c, barrier state -------------------
__global__ void k_init(const float* __restrict__ h0,
                       const float* __restrict__ gW1, const float* __restrict__ gb1,
                       const float* __restrict__ gW2, const float* __restrict__ gb2,
                       const float* __restrict__ gWF, const float* __restrict__ gbF) {
    int blk = blockIdx.x, tid = threadIdx.x;
    if (blk < 256) {
        int idx = blk * 256 + tid;               // [0, 65536)
        float v = h0[idx & (Hsz - 1)];
        g_h[0][0][idx] = v;
        g_h[1][0][idx] = v;
    } else if (blk == 256) {
        __shared__ float red[256];
        float s = 0.f;
        for (int j = tid; j < Hsz; j += 256) s += gWF[j] * (gb1[j] + gb2[j]);
        red[tid] = s;
        __syncthreads();
        for (int off = 128; off > 0; off >>= 1) {
            if (tid < off) red[tid] += red[tid + off];
            __syncthreads();
        }
        if (tid == 0) g_c = red[0] + gbF[0];
        if (tid < 128) { g_bar_cnt[tid] = 0u; g_bar_gen[tid] = 0u; }
    } else if (blk < 261) {
        int k = (blk - 257) * 256 + tid;
        float s = 0.f;
        for (int j = 0; j < Hsz; ++j) s += gWF[j] * gW1[(size_t)j * Hsz + k];
        g_v1[k] = s;
    } else {
        int k = (blk - 261) * 256 + tid;
        float s = 0.f;
        for (int j = 0; j < Hsz; ++j) s += gWF[j] * gW2[(size_t)j * Hsz + k];
        g_v2[k] = s;
    }
}

// ---------------- precompute an[b,t] = x[b, min(t+1,T-1)] . v1 --------------
__global__ void k_an(const float* __restrict__ x) {
    int blk = blockIdx.x, tid = threadIdx.x;
    int lane = tid & 63, wv = tid >> 6;
    for (int i = 0; i < 16; ++i) {
        int o = blk * 64 + wv * 16 + i;      // [0, 16384)
        int b = o >> 8, tt = o & 255;
        int ts = (tt + 1 < Tsz) ? tt + 1 : Tsz - 1;
        const float* xp = x + ((size_t)b * Tsz + ts) * Hsz;
        float s = 0.f;
        for (int k = lane; k < Hsz; k += 64) s += xp[k] * g_v1[k];
        for (int m = 32; m > 0; m >>= 1) s += __shfl_xor(s, m, 64);
        if (lane == 0) g_an[o] = s;
    }
}

__device__ __forceinline__ float dot4(float4 a, float4 b) {
    return a.x * b.x + a.y * b.y + a.z * b.z + a.w * b.w;
}

// ---------------- one GRU layer phase ---------------------------------------
__device__ __forceinline__ void do_phase(
    bool is_l1, int t, int bg, int jg,
    const float* __restrict__ a0base, size_t a0stride,     // gi-input rows
    const float* __restrict__ stbase, float* __restrict__ hout,  // state in/out
    const float* __restrict__ Wih, const float* __restrict__ Whh,
    const float* __restrict__ bi_l, const float* __restrict__ bh_l,
    const float* __restrict__ h0bc, const int* __restrict__ lens,
    float* __restrict__ outp, float* __restrict__ gatep,
    float (*s_act)[2][16][68], float (*s_red)[6][16][16], float* s_rst) {

    const int tid = threadIdx.x;
    const int b0 = bg * 16, jn0 = jg * 16;

    // ---- prologue: reset flags from previous step's gate; write gate_z -----
    if (tid < 16) {
        float rstf = 0.f;
        int b = b0 + tid;
        if (t > 0) {
            int tp = t - 1;
            float pre = g_c + g_an[b * Tsz + tp];
            const float(*pw)[64] = g_preW[tp & 1];
#pragma unroll 8
            for (int j = 0; j < 64; ++j) pre += pw[j][b];
            int lb = lens[b];
            bool il = (tp == lb - 1);
            rstf = (il || pre > 0.f) ? 1.f : 0.f;
            if (!is_l1 && jg == 0) {
                float gt = il ? 1.f : 1.f / (1.f + __expf(-pre));
                gatep[(size_t)b * Tsz + tp] = (tp < lb) ? gt : 0.f;
            }
        }
        s_rst[tid] = rstf;
    }
    __syncthreads();

    const int wv = tid >> 6, lane = tid & 63;
    const int bi2 = (lane & 7) * 2, ji2 = (lane >> 3) * 2;

    // per-thread weight row pointers (fixed for the whole phase)
    const float* wp_i[6];
    const float* wp_h[6];
#pragma unroll
    for (int g = 0; g < 3; ++g)
#pragma unroll
        for (int dj = 0; dj < 2; ++dj) {
            int row = g * Hsz + jn0 + ji2 + dj;
            wp_i[g * 2 + dj] = Wih + (size_t)row * Hsz;
            wp_h[g * 2 + dj] = Whh + (size_t)row * Hsz;
        }

    float acc_i[2][2][3] = {};
    float acc_h[2][2][3] = {};
    const int kq0 = wv * 256;   // this wave's K quarter

    for (int c = 0; c < 4; ++c) {
        const int kb = kq0 + c * 64;
        // stage activations (transposed into per-wave LDS slice)
#pragma unroll
        for (int rr = 0; rr < 4; ++rr) {
            int f = lane + 64 * rr;
            int bb = f >> 4, kq = (f & 15) * 4;
            float4 va = *(const float4*)(a0base + (size_t)(b0 + bb) * a0stride + (kb + kq));
            *(float4*)&s_act[wv][0][bb][kq] = va;
            float4 vs = *(const float4*)(stbase + (size_t)(b0 + bb) * Hsz + (kb + kq));
            if (s_rst[bb] != 0.f) vs = *(const float4*)(h0bc + kb + kq);
            *(float4*)&s_act[wv][1][bb][kq] = vs;
        }
        // compute (weights direct from global: 8-way wave-broadcast, L1/L2 hot)
#pragma unroll 2
        for (int kk = 0; kk < 64; kk += 4) {
            float4 xA = *(const float4*)&s_act[wv][0][bi2][kk];
            float4 xB = *(const float4*)&s_act[wv][0][bi2 + 1][kk];
            float4 hA = *(const float4*)&s_act[wv][1][bi2][kk];
            float4 hB = *(const float4*)&s_act[wv][1][bi2 + 1][kk];
            int k = kb + kk;
#pragma unroll
            for (int g = 0; g < 3; ++g)
#pragma unroll
                for (int dj = 0; dj < 2; ++dj) {
                    float4 wi = *(const float4*)(wp_i[g * 2 + dj] + k);
                    float4 wh = *(const float4*)(wp_h[g * 2 + dj] + k);
                    acc_i[0][dj][g] += dot4(xA, wi);
                    acc_i[1][dj][g] += dot4(xB, wi);
                    acc_h[0][dj][g] += dot4(hA, wh);
                    acc_h[1][dj][g] += dot4(hB, wh);
                }
        }
    }

    // ---- cross-wave reduce -------------------------------------------------
    __syncthreads();
#pragma unroll
    for (int db = 0; db < 2; ++db)
#pragma unroll
        for (int dj = 0; dj < 2; ++dj) {
            int bI = bi2 + db, jI = ji2 + dj;
#pragma unroll
            for (int g = 0; g < 3; ++g) {
                s_red[wv][g][bI][jI] = acc_i[db][dj][g];
                s_red[wv][3 + g][bI][jI] = acc_h[db][dj][g];
            }
        }
    __syncthreads();

    // ---- epilogue: GRU cell math, state/output/gate writes -----------------
    {
        int ji = tid & 15, bi = tid >> 4;
        int b = b0 + bi, jn = jn0 + ji;
        float sir = 0, siz = 0, sin_ = 0, shr = 0, shz = 0, shn = 0;
#pragma unroll
        for (int w = 0; w < 4; ++w) {
            sir += s_red[w][0][bi][ji];
            siz += s_red[w][1][bi][ji];
            sin_ += s_red[w][2][bi][ji];
            shr += s_red[w][3][bi][ji];
            shz += s_red[w][4][bi][ji];
            shn += s_red[w][5][bi][ji];
        }
        float gir = sir + bi_l[jn], giz = siz + bi_l[Hsz + jn], gin = sin_ + bi_l[2 * Hsz + jn];
        float ghr = shr + bh_l[jn], ghz = shz + bh_l[Hsz + jn], ghn = shn + bh_l[2 * Hsz + jn];
        float r = 1.f / (1.f + __expf(-(gir + ghr)));
        float z = 1.f / (1.f + __expf(-(giz + ghz)));
        float n = tanhf(gin + r * ghn);
        float hprev = stbase[(size_t)b * Hsz + jn];
        if (s_rst[bi] != 0.f) hprev = h0bc[jn];
        float hnew = (1.f - z) * n + z * hprev;
        hout[(size_t)b * Hsz + jn] = hnew;
        if (is_l1) {
            outp[((size_t)b * Tsz + t) * Hsz + jn] = (t < lens[b]) ? hnew : 0.f;
            float prod = hnew * g_v2[jn];
            __syncthreads();                       // done reading s_red
            float* sc = &s_red[0][0][0][0];
            sc[bi * 16 + ji] = prod;
            __syncthreads();
            if (tid < 16) {
                float s = 0.f;
#pragma unroll
                for (int j = 0; j < 16; ++j) s += sc[tid * 16 + j];
                g_preW[t & 1][jg][b0 + tid] = s;
            }
        }
    }
}

// ---------------- main persistent cooperative kernel ------------------------
__global__ void __launch_bounds__(NTHR, 1)
k_main(const float* __restrict__ x, const float* __restrict__ h0,
       const int* __restrict__ lens,
       const float* __restrict__ W_ih, const float* __restrict__ W_hh,
       const float* __restrict__ b_ih, const float* __restrict__ b_hh,
       float* __restrict__ outp, float* __restrict__ gatep) {
    __shared__ __align__(16) float s_act[4][2][16][68];  // 34.8 KB
    __shared__ float s_red[4][6][16][16];                // 24.6 KB
    __shared__ float s_rst[16];

    int wg = blockIdx.x, bg = wg >> 6, jg = wg & 63;
    unsigned lgen = 0;
    const float* Wih1 = W_ih + (size_t)3 * Hsz * Hsz;
    const float* Whh1 = W_hh + (size_t)3 * Hsz * Hsz;
    const float* bi1 = b_ih + 3 * Hsz;
    const float* bh1 = b_hh + 3 * Hsz;

    for (int t = 0; t < Tsz; ++t) {
        int p0 = t & 1, p1 = p0 ^ 1;
        // layer 0: gi from x_t, gh from h0 state
        do_phase(false, t, bg, jg,
                 x + (size_t)t * Hsz, (size_t)Tsz * Hsz,
                 g_h[0][p0], g_h[0][p1],
                 W_ih, W_hh, b_ih, b_hh, h0, lens,
                 outp, gatep, s_act, s_red, s_rst);
        groupbar(bg, ++lgen);
        // layer 1: gi from fresh h0new, gh from h1 state
        do_phase(true, t, bg, jg,
                 g_h[0][p1], (size_t)Hsz,
                 g_h[1][p0], g_h[1][p1],
                 Wih1, Whh1, bi1, bh1, h0, lens,
                 outp, gatep, s_act, s_red, s_rst);
        groupbar(bg, ++lgen);
    }
    // tail: gate_z for t = T-1
    if (jg == 0 && threadIdx.x < 16) {
        int b = bg * 16 + (int)threadIdx.x;
        float pre = g_c + g_an[b * Tsz + (Tsz - 1)];
        for (int j = 0; j < 64; ++j) pre += g_preW[(Tsz - 1) & 1][j][b];
        int lb = lens[b];
        bool il = ((Tsz - 1) == lb - 1);
        float gt = il ? 1.f : 1.f / (1.f + __expf(-pre));
        gatep[(size_t)b * Tsz + (Tsz - 1)] = ((Tsz - 1) < lb) ? gt : 0.f;
    }
}

// ---------------- host launcher ---------------------------------------------
extern "C" void kernel_launch(void* const* d_in, const int* in_sizes, int n_in,
                              void* d_out, int out_size, void* d_ws, size_t ws_size,
                              hipStream_t stream) {
    const float* x = (const float*)d_in[0];
    const float* h0 = (const float*)d_in[1];
    const int* lens = (const int*)d_in[2];
    const float* W_ih = (const float*)d_in[3];
    const float* W_hh = (const float*)d_in[4];
    const float* b_ih = (const float*)d_in[5];
    const float* b_hh = (const float*)d_in[6];
    const float* gW1 = (const float*)d_in[7];
    const float* gb1 = (const float*)d_in[8];
    const float* gW2 = (const float*)d_in[9];
    const float* gb2 = (const float*)d_in[10];
    const float* gWF = (const float*)d_in[11];
    const float* gbF = (const float*)d_in[12];
    float* outp = (float*)d_out;
    float* gatep = outp + (size_t)Bsz * Tsz * Hsz;

    hipLaunchKernelGGL(k_init, dim3(265), dim3(256), 0, stream,
                       h0, gW1, gb1, gW2, gb2, gWF, gbF);
    hipLaunchKernelGGL(k_an, dim3(256), dim3(256), 0, stream, x);

    void* args[9] = { (void*)&x, (void*)&h0, (void*)&lens, (void*)&W_ih, (void*)&W_hh,
                      (void*)&b_ih, (void*)&b_hh, (void*)&outp, (void*)&gatep };
    hipError_t err = hipLaunchCooperativeKernel((const void*)k_main, dim3(NWG), dim3(NTHR),
                                                args, 0, stream);
    (void)err;
}